// Round 10
// baseline (138.518 us; speedup 1.0000x reference)
//
#include <hip/hip_runtime.h>
#include <stdint.h>

#define HH 8192           // B*H = 16*512 strip height
#define WW 512            // width
#define WPR 8             // uint64 words per row (512/64)
#define TG22F 0.4142135623730951f
#define NSWEEP 5

typedef float vf4 __attribute__((ext_vector_type(4)));   // native vec for nontemporal builtins

// ---- workspace layout (bytes) ----
// packed u16 mag|dir<<12 : 8 MiB   @ 0
// buf (strong, in-place) : 512 KiB @ 8388608
// weak bitmap            : 512 KiB @ 8912896
// flags (16 ints)        : 64 B    @ 9437184

__device__ __forceinline__ float to_img(float v) {
    float t = floorf((v + 1.0f) * 0.5f * 255.0f);
    return fminf(fmaxf(t, 0.0f), 255.0f);
}

__device__ __forceinline__ int bsel(uint64_t w0, uint64_t w1, int idx) {
    return (idx < 8) ? (int)((w0 >> (idx * 8)) & 255)
                     : (int)((w1 >> ((idx - 8) * 8)) & 255);
}

// Fill all bits of runs of `w` that contain at least one bit of `s`.
__device__ __forceinline__ uint64_t runfill(uint64_t s, uint64_t w) {
    uint64_t sw = s & w;
    uint64_t up = ((sw + w) ^ w) & w;
    uint64_t rs = __brevll(sw);
    uint64_t rw = __brevll(w);
    uint64_t dn = __brevll(((rs + rw) ^ rw) & rw);
    return up | dn | sw;
}

// 64-bit shuffles via two 32-bit halves (avoid 64-bit shfl overloads).
__device__ __forceinline__ uint64_t shfl_up64(uint64_t v, int d) {
    int lo = __shfl_up((int)(uint32_t)v, d, 64);
    int hi = __shfl_up((int)(uint32_t)(v >> 32), d, 64);
    return ((uint64_t)(uint32_t)hi << 32) | (uint32_t)lo;
}
__device__ __forceinline__ uint64_t shfl_dn64(uint64_t v, int d) {
    int lo = __shfl_down((int)(uint32_t)v, d, 64);
    int hi = __shfl_down((int)(uint32_t)(v >> 32), d, 64);
    return ((uint64_t)(uint32_t)hi << 32) | (uint32_t)lo;
}

// Kernel 1: quantize + Sobel (replicate pad on strip) + channel argmax + dir.
// (Round-8 passing version; input loads non-temporal — 50 MB one-touch.)
__global__ void k_sobel(const float* __restrict__ in, uint16_t* __restrict__ packed) {
    __shared__ uint8_t simg[3 * 34 * 72];
    const int tid = threadIdx.x;
    const int row0 = (blockIdx.x >> 3) << 5;
    const int col0 = (blockIdx.x & 7) << 6;

    for (int i = tid; i < 1632; i += 256) {
        int c = i / 544;
        int rem = i - c * 544;
        int hr = rem >> 4;
        int q = rem & 15;
        int gy = row0 + hr - 1;
        gy = gy < 0 ? 0 : (gy >= HH ? HH - 1 : gy);
        int b = gy >> 9, h = gy & 511;
        const vf4 v = __builtin_nontemporal_load(
            (const vf4*)&in[((((b * 3 + c) << 9) + h) << 9) + col0 + (q << 2)]);
        uint32_t pk = (uint32_t)(uint8_t)to_img(v.x)
                    | ((uint32_t)(uint8_t)to_img(v.y) << 8)
                    | ((uint32_t)(uint8_t)to_img(v.z) << 16)
                    | ((uint32_t)(uint8_t)to_img(v.w) << 24);
        *(uint32_t*)&simg[(c * 34 + hr) * 72 + 4 + (q << 2)] = pk;
    }
    for (int i = tid; i < 204; i += 256) {
        int c = i / 68;
        int rem = i - c * 68;
        int hr = rem >> 1;
        int side = rem & 1;
        int gy = row0 + hr - 1;
        gy = gy < 0 ? 0 : (gy >= HH ? HH - 1 : gy);
        int gc = side ? col0 + 64 : col0 - 1;
        gc = gc < 0 ? 0 : (gc >= WW ? WW - 1 : gc);
        int b = gy >> 9, h = gy & 511;
        float v = to_img(in[((((b * 3 + c) << 9) + h) << 9) + gc]);
        simg[(c * 34 + hr) * 72 + (side ? 68 : 3)] = (uint8_t)v;
    }
    __syncthreads();

    const int r = tid >> 3;
    const int c8 = (tid & 7) << 3;

    int bestMag[8], bgx[8], bgy[8];
    #pragma unroll
    for (int j = 0; j < 8; ++j) { bestMag[j] = -1; bgx[j] = 0; bgy[j] = 0; }

    #pragma unroll
    for (int c = 0; c < 3; ++c) {
        const uint8_t* base = &simg[(c * 34 + r) * 72 + c8];
        uint64_t w00 = *(const uint64_t*)(base);
        uint64_t w01 = *(const uint64_t*)(base + 8);
        uint64_t w10 = *(const uint64_t*)(base + 72);
        uint64_t w11 = *(const uint64_t*)(base + 80);
        uint64_t w20 = *(const uint64_t*)(base + 144);
        uint64_t w21 = *(const uint64_t*)(base + 152);
        int vs[10], t0[10], t2[10];
        #pragma unroll
        for (int i = 0; i < 10; ++i) {
            int a0 = bsel(w00, w01, 3 + i);
            int a1 = bsel(w10, w11, 3 + i);
            int a2 = bsel(w20, w21, 3 + i);
            vs[i] = a0 + 2 * a1 + a2;
            t0[i] = a0; t2[i] = a2;
        }
        #pragma unroll
        for (int j = 0; j < 8; ++j) {
            int gx = vs[j + 2] - vs[j];
            int gy = (t2[j] + 2 * t2[j + 1] + t2[j + 2]) - (t0[j] + 2 * t0[j + 1] + t0[j + 2]);
            int mg = abs(gx) + abs(gy);
            if (mg > bestMag[j]) { bestMag[j] = mg; bgx[j] = gx; bgy[j] = gy; }
        }
    }

    uint32_t res[4];
    #pragma unroll
    for (int jj = 0; jj < 4; ++jj) {
        uint32_t pair = 0;
        #pragma unroll
        for (int s = 0; s < 2; ++s) {
            int j = jj * 2 + s;
            float axf = (float)abs(bgx[j]);
            float ayf = (float)abs(bgy[j]);
            int dir;
            if (ayf < TG22F * axf)      dir = 0;
            else if (ayf * TG22F > axf) dir = 1;
            else                        dir = (bgx[j] * bgy[j] >= 0) ? 2 : 3;
            uint32_t val = (uint32_t)(bestMag[j] | (dir << 12));
            pair |= val << (s * 16);
        }
        res[jj] = pair;
    }
    int y = row0 + r;
    *(uint4*)&packed[y * WW + col0 + c8] = *(uint4*)res;   // normal store: k_nms re-reads via L2
}

// Kernel 2: NMS (zero pad on strip) -> strong/weak bitmaps via wave ballot.
// Also zeroes the sweep flags (block 0 only). (Round-5/8 passing, verbatim.)
__global__ void k_nms(const uint16_t* __restrict__ packed,
                      unsigned long long* __restrict__ strongB,
                      unsigned long long* __restrict__ weakB,
                      int* __restrict__ flags) {
    if (blockIdx.x == 0 && threadIdx.x < 16) flags[threadIdx.x] = 0;
    int y = blockIdx.x >> 1;
    int x = ((blockIdx.x & 1) << 8) + threadIdx.x;
    uint16_t own = packed[y * WW + x];
    int mag = own & 0xFFF;
    int dir = own >> 12;
    int d1y = (dir == 0) ? 0 : -1;
    int d1x = (dir == 0) ? -1 : (dir == 1) ? 0 : (dir == 2) ? -1 : 1;
    int n1y = y + d1y, n1x = x + d1x;
    int n2y = y - d1y, n2x = x - d1x;
    int n1 = (n1y >= 0 && n1y < HH && n1x >= 0 && n1x < WW) ? (packed[n1y * WW + n1x] & 0xFFF) : 0;
    int n2 = (n2y >= 0 && n2y < HH && n2x >= 0 && n2x < WW) ? (packed[n2y * WW + n2x] & 0xFFF) : 0;
    bool keep = (mag > n1) && (mag >= n2);
    bool strong = keep && (mag > 200);
    bool weak   = keep && (mag > 100);
    unsigned long long sb = __ballot(strong ? 1 : 0);
    unsigned long long wb = __ballot(weak ? 1 : 0);
    if ((threadIdx.x & 63) == 0) {
        int word = y * WPR + (x >> 6);
        strongB[word] = sb;
        weakB[word]   = wb;
    }
}

// Kernel 3: wave-local hysteresis sweep (round-8 passing, verbatim).
__global__ void __launch_bounds__(256) k_wsweep(
        const unsigned long long* __restrict__ weakB,
        unsigned long long* __restrict__ buf,
        int* __restrict__ flags, int sidx)
{
    if (sidx > 0 && flags[sidx - 1] == 0) return;
    const int lane = threadIdx.x & 63;
    const int wave = (blockIdx.x << 2) + (threadIdx.x >> 6);   // 0..127
    const int base = ((wave << 6) + lane) * WPR;               // own row

    uint64_t own[8], wk[8];
    #pragma unroll
    for (int k = 0; k < 8; ++k) { wk[k] = weakB[base + k]; own[k] = buf[base + k]; }

    uint64_t hu[8], hd[8];
    #pragma unroll
    for (int k = 0; k < 8; ++k) { hu[k] = 0; hd[k] = 0; }
    if (lane == 0 && wave > 0) {
        #pragma unroll
        for (int k = 0; k < 8; ++k) hu[k] = buf[base - WPR + k];
    }
    if (lane == 63 && wave < 127) {
        #pragma unroll
        for (int k = 0; k < 8; ++k) hd[k] = buf[base + WPR + k];
    }
    uint64_t hspu[8], hspd[8];
    #pragma unroll
    for (int k = 0; k < 8; ++k) {
        uint64_t a = hu[k] | (hu[k] << 1) | (hu[k] >> 1);
        if (k > 0) a |= hu[k - 1] >> 63;
        if (k < 7) a |= hu[k + 1] << 63;
        hspu[k] = a;
        uint64_t b = hd[k] | (hd[k] << 1) | (hd[k] >> 1);
        if (k > 0) b |= hd[k - 1] >> 63;
        if (k < 7) b |= hd[k + 1] << 63;
        hspd[k] = b;
    }

    bool grew = false;
    for (;;) {
        uint64_t sp[8];
        #pragma unroll
        for (int k = 0; k < 8; ++k) {
            uint64_t h = own[k] | (own[k] << 1) | (own[k] >> 1);
            if (k > 0) h |= own[k - 1] >> 63;
            if (k < 7) h |= own[k + 1] << 63;
            sp[k] = h;
        }
        uint64_t su[8], sd[8];
        #pragma unroll
        for (int k = 0; k < 8; ++k) {
            su[k] = shfl_up64(sp[k], 1);
            sd[k] = shfl_dn64(sp[k], 1);
        }
        if (lane == 0) {
            #pragma unroll
            for (int k = 0; k < 8; ++k) su[k] = hspu[k];
        }
        if (lane == 63) {
            #pragma unroll
            for (int k = 0; k < 8; ++k) sd[k] = hspd[k];
        }
        uint32_t ch = 0;
        #pragma unroll
        for (int k = 0; k < 8; ++k) {
            uint64_t acc = sp[k] | su[k] | sd[k];
            uint64_t nv = runfill(own[k] | (acc & wk[k]), wk[k]);
            ch |= (uint32_t)(nv != own[k]);
            own[k] = nv;
        }
        if (ch) grew = true;
        if (__ballot(ch ? 1 : 0) == 0ull) break;   // wave-uniform
    }

    if (__ballot(grew ? 1 : 0) != 0ull) {
        #pragma unroll
        for (int k = 0; k < 8; ++k) buf[base + k] = own[k];
        if (lane == 0)
            __hip_atomic_store(&flags[sidx], 1, __ATOMIC_RELAXED, __HIP_MEMORY_SCOPE_AGENT);
    }
}

// Kernel 4: expand bitmap -> (16,3,512,512) f32 output in {-1,+1}.
// Non-temporal 16B stores: 50 MB one-touch write stream.
__global__ void k_out(const unsigned long long* __restrict__ result, float* __restrict__ out) {
    int t = blockIdx.x * blockDim.x + threadIdx.x;
    int b = t >> 16;
    int r = t & 65535;
    int h = r >> 7;
    int w = (r & 127) << 2;
    int y = (b << 9) + h;
    unsigned long long word = result[y * WPR + (w >> 6)];
    int sh = w & 63;
    vf4 v;
    v.x = ((word >> (sh + 0)) & 1ull) ? 1.0f : -1.0f;
    v.y = ((word >> (sh + 1)) & 1ull) ? 1.0f : -1.0f;
    v.z = ((word >> (sh + 2)) & 1ull) ? 1.0f : -1.0f;
    v.w = ((word >> (sh + 3)) & 1ull) ? 1.0f : -1.0f;
    int base = (b * 3) << 18;
    int off = (h << 9) + w;
    __builtin_nontemporal_store(v, (vf4*)&out[base + off]);
    __builtin_nontemporal_store(v, (vf4*)&out[base + 262144 + off]);
    __builtin_nontemporal_store(v, (vf4*)&out[base + 524288 + off]);
}

extern "C" void kernel_launch(void* const* d_in, const int* in_sizes, int n_in,
                              void* d_out, int out_size, void* d_ws, size_t ws_size,
                              hipStream_t stream) {
    const float* x = (const float*)d_in[0];
    float* out = (float*)d_out;
    char* ws = (char*)d_ws;

    uint16_t* packed          = (uint16_t*)(ws);
    unsigned long long* buf   = (unsigned long long*)(ws + 8388608);
    unsigned long long* weakB = (unsigned long long*)(ws + 8912896);
    int* flags                = (int*)(ws + 9437184);

    k_sobel<<<2048, 256, 0, stream>>>(x, packed);
    k_nms<<<HH * 2, 256, 0, stream>>>(packed, buf, weakB, flags);
    for (int s = 0; s < NSWEEP; ++s)
        k_wsweep<<<32, 256, 0, stream>>>(weakB, buf, flags, s);
    k_out<<<4096, 256, 0, stream>>>(buf, out);
}